// Round 22
// baseline (515.381 us; speedup 1.0000x reference)
//
#include <hip/hip_runtime.h>

#define BB 128
#define CH 16
#define NBANDS 100
#define OUTC 10

// bf16 activation padded geometry: [12 e'][12 f'][11 g'][11 h']; valid e',f' in [1,10], g',h' in [1,9]
#define P1PLANE 121
#define P1POS   17424   /* 12*12*121 */

// fp32 L1-input padded geometry: [12 e'][12 f'][11 g'][12 h'] (h padded to 12 for float4 rows)
#define PFPLANE 132     /* 11*12 */
#define PFPOS   19008   /* 12*12*132 */

// conv_mfma LDS: split-half layout, DOUBLE-BUFFERED. Per buffer: two regions (ci 0..7 / 8..15),
// each [16 planes][11 g][12 h] x 16B = 33792 B, +16B front guard +16B tail = 67616 B.
// Two buffers = 135232 B -> 1 block/CU. Slot(half,pl,g,h) = 16 + half*REGSZ + (pl*132+g*12+h)*16.
#define REGSZ   33792
#define LDSBUF  (16 + 2*REGSZ + 16)
#define NCHUNK  (16*132)    /* 2112 position chunks per tile */
#define NKP     5           /* 9 (de,df) combos -> 5 K=32 pairs (last half dummy) */
#define WPL4    (NKP*9*64)  /* uint4 per layer = 2880 */
#define NBATCH  4           /* batches chained per block (double-buffered) */

typedef unsigned short ushort_t;
typedef unsigned int uint_t;
typedef __attribute__((ext_vector_type(8))) short short8;
typedef __attribute__((ext_vector_type(4))) float f32x4;

__device__ __forceinline__ ushort_t f2bf(float f) {
    unsigned u = __float_as_uint(f);
    unsigned r = u + 0x7fffu + ((u >> 16) & 1u);   // RNE
    return (ushort_t)(r >> 16);
}
__device__ __forceinline__ uint_t pk2(float a, float b) {
    return (uint_t)f2bf(a) | ((uint_t)f2bf(b) << 16);
}

// DPP shift within 16-lane rows. row_shl:1 (0x101): dst[n]=src[n+1], bound_ctrl -> 0 at row edge.
template<int CTRL>
__device__ __forceinline__ short8 dpp_shift(short8 v) {
    union { short8 s; int i[4]; } a, b;
    a.s = v;
    #pragma unroll
    for (int k = 0; k < 4; ++k)
        b.i[k] = __builtin_amdgcn_update_dpp(0, a.i[k], CTRL, 0xf, 0xf, true);
    return b.s;
}

// ---------------- prep: local = x - center -> h12-padded fp32, zero-fills pads ----------------
__global__ void prep_kernel(const float* __restrict__ x, float* __restrict__ bufP, int nb) {
    int idx = blockIdx.x * 256 + threadIdx.x;
    if (idx >= nb * PFPOS) return;
    int pos = idx % PFPOS;
    int b = idx / PFPOS;
    int e = pos / 1584;          /* 12*132 */
    int r = pos % 1584;
    int f = r / 132;
    int s = r % 132;
    int g = s / 12, h = s % 12;
    float v = 0.f;
    if (e >= 1 && e <= 10 && f >= 1 && f <= 10 && g >= 1 && g <= 9 && h >= 1 && h <= 9) {
        const float* xp = x + ((size_t)b * NBANDS + (e - 1) * 10 + (f - 1)) * 81;
        v = xp[(g - 1) * 9 + (h - 1)] - xp[40];
    }
    bufP[idx] = v;
}

// ---------------- pack weights, all 4 layers: [4][5 kp][9 dgdh][64 lane] x 16B ----------------
__global__ void pack_w_kernel(const float* __restrict__ w2, const float* __restrict__ w3,
                              const float* __restrict__ w4, const float* __restrict__ w5,
                              uint4* __restrict__ wp) {
    int t = blockIdx.x * 256 + threadIdx.x;
    if (t >= WPL4) return;
    int layer = blockIdx.y;
    const float* w = (layer == 0) ? w2 : (layer == 1) ? w3 : (layer == 2) ? w4 : w5;
    int l = t & 63, pd = t >> 6;
    int kp = pd / 9, q = pd % 9;
    int co = l & 15, kh = l >> 4;
    int m = kh >> 1, cih = (kh & 1) * 8;
    int c = 2 * kp + m;
    uint_t r[4] = {0, 0, 0, 0};
    if (c <= 8) {
        int tap = c * 9 + q;     // de*27+df*9+dg*3+dh
        #pragma unroll
        for (int jj = 0; jj < 4; ++jj) {
            ushort_t lo = f2bf(w[(co * 16 + cih + 2 * jj) * 81 + tap]);
            ushort_t hi = f2bf(w[(co * 16 + cih + 2 * jj + 1) * 81 + tap]);
            r[jj] = (uint_t)lo | ((uint_t)hi << 16);
        }
    }
    uint4 v; v.x = r[0]; v.y = r[1]; v.z = r[2]; v.w = r[3];
    wp[(size_t)layer * WPL4 + t] = v;
}

// ---------------- L1: cin=1 fp32 conv, co-split 4 (R19 proven form) ----------------
__global__ __launch_bounds__(256) void conv1_kernel(
    const float* __restrict__ in, const float* __restrict__ w,
    const float* __restrict__ bias, ushort_t* __restrict__ out) {
    int idx = blockIdx.x * 256 + threadIdx.x;
    if (idx >= 900) return;
    int b = blockIdx.z;
    int co0 = blockIdx.y * 4;
    int g = idx % 9;
    int f = (idx / 9) % 10;
    int e = idx / 90;

    float acc[4][9];
    #pragma unroll
    for (int co = 0; co < 4; ++co) {
        float bv = bias[co0 + co];
        #pragma unroll
        for (int h = 0; h < 9; ++h) acc[co][h] = bv;
    }

    const float* ip = in + (size_t)b * PFPOS;
    #pragma unroll
    for (int de = 0; de < 3; ++de)
    #pragma unroll
    for (int df = 0; df < 3; ++df)
    #pragma unroll
    for (int dg = 0; dg < 3; ++dg) {
        const float4* rp4 = (const float4*)(ip + ((e + de) * 12 + (f + df)) * PFPLANE + (g + dg) * 12);
        float4 r0 = rp4[0], r1 = rp4[1], r2 = rp4[2];
        float v[12] = {r0.x, r0.y, r0.z, r0.w, r1.x, r1.y, r1.z, r1.w, r2.x, r2.y, r2.z, r2.w};
        #pragma unroll
        for (int dh = 0; dh < 3; ++dh) {
            int tap = de * 27 + df * 9 + dg * 3 + dh;
            #pragma unroll
            for (int co = 0; co < 4; ++co) {
                float ws = w[(co0 + co) * 81 + tap];
                #pragma unroll
                for (int h = 0; h < 9; ++h)
                    acc[co][h] = fmaf(ws, v[h + dh], acc[co][h]);
            }
        }
    }

    ushort_t* op = out + ((size_t)b * P1POS + ((e + 1) * 12 + (f + 1)) * P1PLANE + (g + 1) * 11 + 1) * 16 + co0;
    #pragma unroll
    for (int h = 0; h < 9; ++h) {
        uint2 q;
        q.x = pk2(fmaxf(acc[0][h], 0.f), fmaxf(acc[1][h], 0.f));
        q.y = pk2(fmaxf(acc[2][h], 0.f), fmaxf(acc[3][h], 0.f));
        *(uint2*)(op + h * 16) = q;
    }
}

// ---------------- per-wave half-column compute: linear LDS, a0 via offset read (R21 proven) ----------------
template<int GO0, int NT, int GI0, int GI1>
__device__ __forceinline__ void conv_col(
    const char* __restrict__ sIn, const short8* __restrict__ wv8, int l, int we, int wf,
    float bv, int e_out, int f_out, ushort_t* __restrict__ gout) {

    int h = l & 15, kh = l >> 4;
    int m = kh >> 1;                   // K-pair member -> (de,df) select
    int halfoff = (kh & 1) * REGSZ;    // ci half region
    int co = l & 15;

    f32x4 acc[NT];
    #pragma unroll
    for (int t = 0; t < NT; ++t) acc[t] = f32x4{bv, bv, bv, bv};

    #pragma unroll 1
    for (int kp = 0; kp < NKP; ++kp) {
        int c = 2 * kp + m; if (c > 8) c = 8;   // dummy member: valid plane, zero weights
        int pl = (we + c / 3) * 4 + (wf + c % 3);
        int base = halfoff + pl * 2112 + h * 16;   // slot(h) - 16 (incl. guard shift)

        short8 Bf[9];
        #pragma unroll
        for (int q = 0; q < 9; ++q) Bf[q] = wv8[(kp * 9 + q) * 64 + l];

        #pragma unroll
        for (int gi = GI0; gi <= GI1; ++gi) {
            const char* a = sIn + base + gi * 192;
            short8 a0 = *(const short8*)(a);        // slot(h-1): dh=0 operand
            short8 a1 = *(const short8*)(a + 16);   // slot(h):   dh=1 operand
            short8 a2 = dpp_shift<0x101>(a1);       // h+1:       dh=2 operand
            #pragma unroll
            for (int dg = 0; dg < 3; ++dg) {
                int go = gi + 1 - dg;               // compile-time after unroll
                if (go >= GO0 && go < GO0 + NT) {
                    int t = go - GO0;
                    acc[t] = __builtin_amdgcn_mfma_f32_16x16x32_bf16(a0, Bf[dg * 3 + 0], acc[t], 0, 0, 0);
                    acc[t] = __builtin_amdgcn_mfma_f32_16x16x32_bf16(a1, Bf[dg * 3 + 1], acc[t], 0, 0, 0);
                    acc[t] = __builtin_amdgcn_mfma_f32_16x16x32_bf16(a2, Bf[dg * 3 + 2], acc[t], 0, 0, 0);
                }
            }
        }
    }

    // store: D col = lane&15 = co, row = kh*4+reg = h'; keep h' in [1,9]
    #pragma unroll
    for (int t = 0; t < NT; ++t) {
        int go = GO0 + t;
        int base2 = ((e_out * 12 + f_out) * P1PLANE + go * 11) * 16 + co;
        #pragma unroll
        for (int reg = 0; reg < 4; ++reg) {
            int rr = kh * 4 + reg;
            if (rr >= 1 && rr <= 9)
                gout[base2 + rr * 16] = f2bf(fmaxf(acc[t][reg], 0.f));
        }
    }
}

// ---------------- MFMA conv: double-buffered batch chain, async-split staging ----------------
// block = (eb x fb tile, batch group of 4). Loop: issue loads(t+1) | compute(t) | write LDS(t+1) | barrier.
__global__ __launch_bounds__(512, 2) void conv_mfma_kernel(
    const ushort_t* __restrict__ in, const uint4* __restrict__ wp,
    const float* __restrict__ bias, ushort_t* __restrict__ out, int nb) {

    __shared__ __align__(16) char sIn[2 * LDSBUF];   // 135232 B -> 1 block/CU

    int tid = threadIdx.x;
    int b0 = blockIdx.y * NBATCH;
    int eb = (blockIdx.x / 5) * 2;
    int fb = (blockIdx.x % 5) * 2;

    // ---- per-thread chunk descriptors (block-invariant: only global base changes per batch) ----
    bool vals[5];
    int  goffs[5];
    #pragma unroll
    for (int k = 0; k < 5; ++k) {
        int i = tid + k * 512;                 // chunk index; k==4 tail only for tid<64
        bool inrange = (k < 4) | (tid < 64);
        int h = i % 12;
        int gp = i / 12;
        int g = gp % 11;
        int pl = gp / 11;
        int e2 = eb + (pl >> 2), f2 = fb + (pl & 3);
        vals[k] = inrange & (e2 >= 1) & (e2 <= 10) & (f2 >= 1) & (f2 <= 10) &
                  (g >= 1) & (g <= 9) & (h >= 1) & (h <= 9);
        goffs[k] = ((e2 * 12 + f2) * P1PLANE + g * 11 + h) * 16;
    }

    uint4 q0[5], q1[5];
    auto stage_load = [&](const ushort_t* gin) {
        #pragma unroll
        for (int k = 0; k < 5; ++k) {
            q0[k] = make_uint4(0, 0, 0, 0); q1[k] = q0[k];
            if (vals[k]) {
                const uint4* g4 = (const uint4*)(gin + goffs[k]);
                q0[k] = g4[0]; q1[k] = g4[1];
            }
        }
    };
    auto stage_write = [&](char* buf) {
        #pragma unroll
        for (int k = 0; k < 5; ++k) {
            if (k < 4 || tid < 64) {
                int i = tid + k * 512;
                *(uint4*)(buf + 16 + i * 16)         = q0[k];
                *(uint4*)(buf + 16 + REGSZ + i * 16) = q1[k];
            }
        }
    };

    int l = tid & 63, wv = tid >> 6;   // 0..7
    int col = wv >> 1, gs = wv & 1;    // column 0..3, g-half
    int we = col >> 1, wf = col & 1;
    int e_out = eb + 1 + we;
    int f_out = fb + 1 + wf;           // always in [1,10]
    float bv = bias[l & 15];
    const short8* wv8 = (const short8*)wp;

    // ---- prologue: stage batch b0 into buf0 ----
    stage_load(in + (size_t)b0 * (P1POS * 16));
    stage_write(sIn);
    __syncthreads();

    #pragma unroll 1
    for (int t = 0; t < NBATCH; ++t) {
        int b = b0 + t;
        char* bufp = sIn + (size_t)(t & 1) * LDSBUF;

        if (t < NBATCH - 1 && (b + 1) < nb)
            stage_load(in + (size_t)(b + 1) * (P1POS * 16));   // loads in flight during compute

        if (b < nb) {
            ushort_t* gout = out + (size_t)b * (P1POS * 16);
            if (gs == 0)
                conv_col<1, 5, 0, 6>(bufp, wv8, l, we, wf, bv, e_out, f_out, gout);   // go 1..5
            else
                conv_col<6, 4, 5, 10>(bufp, wv8, l, we, wf, bv, e_out, f_out, gout);  // go 6..9
        }

        if (t < NBATCH - 1)
            stage_write(sIn + (size_t)(1 - (t & 1)) * LDSBUF); // vmcnt lands here, after compute

        __syncthreads();
    }
}

// ---------------- fused feat(mean over ef) + fc: one block per b, 8 lanes per gh ----------------
__global__ __launch_bounds__(704) void featfc_kernel(
    const ushort_t* __restrict__ a, const float* __restrict__ fcw,
    const float* __restrict__ fcb, float* __restrict__ out) {
    int t = threadIdx.x;
    if (t >= 648) return;
    int b = blockIdx.x;
    int j = t & 7;          // ci pair index (channels 2j, 2j+1)
    int gh = t >> 3;        // 0..80
    int g = gh / 9, h = gh % 9;
    const uint_t* base = (const uint_t*)(a + (size_t)b * P1POS * 16 +
                                         (size_t)((g + 1) * 11 + (h + 1)) * 16) + j;
    float s0 = 0.f, s1 = 0.f;
    #pragma unroll 2
    for (int e = 1; e <= 10; ++e) {
        #pragma unroll
        for (int f = 1; f <= 10; ++f) {
            uint_t u = base[(size_t)(e * 12 + f) * P1PLANE * 8];
            s0 += __uint_as_float(u << 16);
            s1 += __uint_as_float(u & 0xffff0000u);
        }
    }
    s0 *= 0.01f; s1 *= 0.01f;

    float po[OUTC];
    #pragma unroll
    for (int o = 0; o < OUTC; ++o)
        po[o] = fmaf(fcw[o * 16 + 2 * j], s0, fcw[o * 16 + 2 * j + 1] * s1);
    #pragma unroll
    for (int o = 0; o < OUTC; ++o) {
        po[o] += __shfl_xor(po[o], 1);
        po[o] += __shfl_xor(po[o], 2);
        po[o] += __shfl_xor(po[o], 4);
    }
    out[((size_t)b * OUTC + j) * 81 + gh] = po[j] + fcb[j];
    if (j < 2)
        out[((size_t)b * OUTC + j + 8) * 81 + gh] = po[j + 8] + fcb[j + 8];
}

extern "C" void kernel_launch(void* const* d_in, const int* in_sizes, int n_in,
                              void* d_out, int out_size, void* d_ws, size_t ws_size,
                              hipStream_t stream) {
    const float* x   = (const float*)d_in[0];
    const float* w1  = (const float*)d_in[1];
    const float* b1  = (const float*)d_in[2];
    const float* w2  = (const float*)d_in[3];
    const float* b2  = (const float*)d_in[4];
    const float* w3  = (const float*)d_in[5];
    const float* b3  = (const float*)d_in[6];
    const float* w4  = (const float*)d_in[7];
    const float* b4  = (const float*)d_in[8];
    const float* w5  = (const float*)d_in[9];
    const float* b5  = (const float*)d_in[10];
    const float* fcw = (const float*)d_in[11];
    const float* fcb = (const float*)d_in[12];
    float* outp = (float*)d_out;

    // ---- ws layout ----
    char* wsc = (char*)d_ws;
    uint4* wp_all = (uint4*)wsc;
    size_t off = 4ull * WPL4 * sizeof(uint4);                  // 184 KB

    const size_t perb_bytes = (size_t)PFPOS * 4 + 2ull * P1POS * 16 * 2;
    size_t avail = (ws_size > off) ? ws_size - off : 0;
    int nbmax = (int)(avail / perb_bytes);
    if (nbmax < 1) nbmax = 1;
    if (nbmax > BB) nbmax = BB;

    float* bufP = (float*)(wsc + off);       off += (size_t)nbmax * PFPOS * 4;
    ushort_t* bufA = (ushort_t*)(wsc + off); off += (size_t)nbmax * P1POS * 16 * 2;
    ushort_t* bufB = (ushort_t*)(wsc + off);

    // ---- pack weights for L2..L5 (single launch) ----
    dim3 pg((WPL4 + 255) / 256, 4);
    pack_w_kernel<<<pg, 256, 0, stream>>>(w2, w3, w4, w5, wp_all);

    for (int b0 = 0; b0 < BB; b0 += nbmax) {
        int nb = BB - b0;
        if (nb > nbmax) nb = nbmax;

        int pt = nb * PFPOS;
        prep_kernel<<<(pt + 255) / 256, 256, 0, stream>>>(x + (size_t)b0 * NBANDS * 81, bufP, nb);

        dim3 c1g(4, 4, nb);
        conv1_kernel<<<c1g, 256, 0, stream>>>(bufP, w1, b1, bufA);

        dim3 mg(25, (nb + NBATCH - 1) / NBATCH);
        conv_mfma_kernel<<<mg, 512, 0, stream>>>(bufA, wp_all + 0 * WPL4, b2, bufB, nb);
        conv_mfma_kernel<<<mg, 512, 0, stream>>>(bufB, wp_all + 1 * WPL4, b3, bufA, nb);
        conv_mfma_kernel<<<mg, 512, 0, stream>>>(bufA, wp_all + 2 * WPL4, b4, bufB, nb);
        conv_mfma_kernel<<<mg, 512, 0, stream>>>(bufB, wp_all + 3 * WPL4, b5, bufA, nb);

        featfc_kernel<<<nb, 704, 0, stream>>>(bufA, fcw, fcb, outp + (size_t)b0 * OUTC * 81);
    }
}

// Round 23
// 373.479 us; speedup vs baseline: 1.3799x; 1.3799x over previous
//
#include <hip/hip_runtime.h>

#define BB 128
#define CH 16
#define NBANDS 100
#define OUTC 10

// bf16 activation padded geometry: [12 e'][12 f'][11 g'][11 h']; valid e',f' in [1,10], g',h' in [1,9]
#define P1PLANE 121
#define P1POS   17424   /* 12*12*121 */

// fp32 L1-input padded geometry: [12 e'][12 f'][11 g'][12 h'] (h padded to 12 for float4 rows)
#define PFPLANE 132     /* 11*12 */
#define PFPOS   19008   /* 12*12*132 */

// conv_mfma LDS: split-half layout. Two regions (ci 0..7 / ci 8..15), each
// [16 planes][11 g][12 h] x 16B slots = 33792 B; +16B front guard. Total 67616 B -> 2 blocks/CU.
#define REGSZ   33792
#define LDSTILE (16 + 2*REGSZ + 16)
#define NCHUNK  (16*132)    /* 2112 position chunks */
#define NKP     5           /* 9 (de,df) combos -> 5 K=32 pairs (last half dummy) */
#define WPL4    (NKP*9*64)  /* uint4 per layer = 2880 */

typedef unsigned short ushort_t;
typedef unsigned int uint_t;
typedef __attribute__((ext_vector_type(8))) short short8;
typedef __attribute__((ext_vector_type(4))) float f32x4;

__device__ __forceinline__ ushort_t f2bf(float f) {
    unsigned u = __float_as_uint(f);
    unsigned r = u + 0x7fffu + ((u >> 16) & 1u);   // RNE
    return (ushort_t)(r >> 16);
}
__device__ __forceinline__ uint_t pk2(float a, float b) {
    return (uint_t)f2bf(a) | ((uint_t)f2bf(b) << 16);
}

// DPP shift within 16-lane rows. row_shl:1 (0x101): dst[n]=src[n+1], bound_ctrl -> 0 at row edge.
template<int CTRL>
__device__ __forceinline__ short8 dpp_shift(short8 v) {
    union { short8 s; int i[4]; } a, b;
    a.s = v;
    #pragma unroll
    for (int k = 0; k < 4; ++k)
        b.i[k] = __builtin_amdgcn_update_dpp(0, a.i[k], CTRL, 0xf, 0xf, true);
    return b.s;
}

// ---------------- prep: local = x - center -> h12-padded fp32, zero-fills pads ----------------
__global__ void prep_kernel(const float* __restrict__ x, float* __restrict__ bufP, int nb) {
    int idx = blockIdx.x * 256 + threadIdx.x;
    if (idx >= nb * PFPOS) return;
    int pos = idx % PFPOS;
    int b = idx / PFPOS;
    int e = pos / 1584;          /* 12*132 */
    int r = pos % 1584;
    int f = r / 132;
    int s = r % 132;
    int g = s / 12, h = s % 12;
    float v = 0.f;
    if (e >= 1 && e <= 10 && f >= 1 && f <= 10 && g >= 1 && g <= 9 && h >= 1 && h <= 9) {
        const float* xp = x + ((size_t)b * NBANDS + (e - 1) * 10 + (f - 1)) * 81;
        v = xp[(g - 1) * 9 + (h - 1)] - xp[40];
    }
    bufP[idx] = v;
}

// ---------------- pack weights, all 4 layers: [4][5 kp][9 dgdh][64 lane] x 16B ----------------
__global__ void pack_w_kernel(const float* __restrict__ w2, const float* __restrict__ w3,
                              const float* __restrict__ w4, const float* __restrict__ w5,
                              uint4* __restrict__ wp) {
    int t = blockIdx.x * 256 + threadIdx.x;
    if (t >= WPL4) return;
    int layer = blockIdx.y;
    const float* w = (layer == 0) ? w2 : (layer == 1) ? w3 : (layer == 2) ? w4 : w5;
    int l = t & 63, pd = t >> 6;
    int kp = pd / 9, q = pd % 9;
    int co = l & 15, kh = l >> 4;
    int m = kh >> 1, cih = (kh & 1) * 8;
    int c = 2 * kp + m;
    uint_t r[4] = {0, 0, 0, 0};
    if (c <= 8) {
        int tap = c * 9 + q;     // de*27+df*9+dg*3+dh
        #pragma unroll
        for (int jj = 0; jj < 4; ++jj) {
            ushort_t lo = f2bf(w[(co * 16 + cih + 2 * jj) * 81 + tap]);
            ushort_t hi = f2bf(w[(co * 16 + cih + 2 * jj + 1) * 81 + tap]);
            r[jj] = (uint_t)lo | ((uint_t)hi << 16);
        }
    }
    uint4 v; v.x = r[0]; v.y = r[1]; v.z = r[2]; v.w = r[3];
    wp[(size_t)layer * WPL4 + t] = v;
}

// ---------------- L1: cin=1 fp32 conv, co-split 4 (R19 proven form) ----------------
__global__ __launch_bounds__(256) void conv1_kernel(
    const float* __restrict__ in, const float* __restrict__ w,
    const float* __restrict__ bias, ushort_t* __restrict__ out) {
    int idx = blockIdx.x * 256 + threadIdx.x;
    if (idx >= 900) return;
    int b = blockIdx.z;
    int co0 = blockIdx.y * 4;
    int g = idx % 9;
    int f = (idx / 9) % 10;
    int e = idx / 90;

    float acc[4][9];
    #pragma unroll
    for (int co = 0; co < 4; ++co) {
        float bv = bias[co0 + co];
        #pragma unroll
        for (int h = 0; h < 9; ++h) acc[co][h] = bv;
    }

    const float* ip = in + (size_t)b * PFPOS;
    #pragma unroll
    for (int de = 0; de < 3; ++de)
    #pragma unroll
    for (int df = 0; df < 3; ++df)
    #pragma unroll
    for (int dg = 0; dg < 3; ++dg) {
        const float4* rp4 = (const float4*)(ip + ((e + de) * 12 + (f + df)) * PFPLANE + (g + dg) * 12);
        float4 r0 = rp4[0], r1 = rp4[1], r2 = rp4[2];
        float v[12] = {r0.x, r0.y, r0.z, r0.w, r1.x, r1.y, r1.z, r1.w, r2.x, r2.y, r2.z, r2.w};
        #pragma unroll
        for (int dh = 0; dh < 3; ++dh) {
            int tap = de * 27 + df * 9 + dg * 3 + dh;
            #pragma unroll
            for (int co = 0; co < 4; ++co) {
                float ws = w[(co0 + co) * 81 + tap];
                #pragma unroll
                for (int h = 0; h < 9; ++h)
                    acc[co][h] = fmaf(ws, v[h + dh], acc[co][h]);
            }
        }
    }

    ushort_t* op = out + ((size_t)b * P1POS + ((e + 1) * 12 + (f + 1)) * P1PLANE + (g + 1) * 11 + 1) * 16 + co0;
    #pragma unroll
    for (int h = 0; h < 9; ++h) {
        uint2 q;
        q.x = pk2(fmaxf(acc[0][h], 0.f), fmaxf(acc[1][h], 0.f));
        q.y = pk2(fmaxf(acc[2][h], 0.f), fmaxf(acc[3][h], 0.f));
        *(uint2*)(op + h * 16) = q;
    }
}

// ---------------- staging: split-half layout, predicated loads, linear writes ----------------
__device__ __forceinline__ void stage_chunk(const ushort_t* __restrict__ gin,
                                            char* __restrict__ sIn, int i, int eb, int fb) {
    int h = i % 12;
    int gp = i / 12;
    int g = gp % 11;
    int pl = gp / 11;
    int pe = pl >> 2, pf = pl & 3;
    int e2 = eb + pe, f2 = fb + pf;
    bool valid = (e2 >= 1) & (e2 <= 10) & (f2 >= 1) & (f2 <= 10) &
                 (g >= 1) & (g <= 9) & (h >= 1) & (h <= 9);
    uint4 q0 = make_uint4(0, 0, 0, 0), q1 = q0;
    if (valid) {
        const uint4* g4 = (const uint4*)(gin + (size_t)((e2 * 12 + f2) * P1PLANE + g * 11 + h) * 16);
        q0 = g4[0]; q1 = g4[1];
    }
    *(uint4*)(sIn + 16 + i * 16)         = q0;   // region0: ci 0..7
    *(uint4*)(sIn + 16 + REGSZ + i * 16) = q1;   // region1: ci 8..15
}

// ---------------- per-wave half-column compute: dh-OUTER MFMA order (chain distance 3) ----------------
// base = half*REGSZ + pl*2112 + h*16 points at slot(h)-16 (guard absorbs pl=0,h=0 underrun).
// a1 = base+16 = slot(h); a0 = slot(h-1) direct read; a2 = DPP shl of a1.
template<int GO0, int NT, int GI0, int GI1>
__device__ __forceinline__ void conv_col(
    const char* __restrict__ sIn, const short8* __restrict__ wv8, int l, int we, int wf,
    float bv, int e_out, int f_out, ushort_t* __restrict__ gout) {

    int h = l & 15, kh = l >> 4;
    int m = kh >> 1;                   // K-pair member -> (de,df) select
    int halfoff = (kh & 1) * REGSZ;    // ci half region
    int co = l & 15;

    f32x4 acc[NT];
    #pragma unroll
    for (int t = 0; t < NT; ++t) acc[t] = f32x4{bv, bv, bv, bv};

    #pragma unroll 1
    for (int kp = 0; kp < NKP; ++kp) {
        int c = 2 * kp + m; if (c > 8) c = 8;   // dummy member: valid plane, zero weights
        int pl = (we + c / 3) * 4 + (wf + c % 3);
        int base = halfoff + pl * 2112 + h * 16;   // slot(h) - 16 (incl. guard shift)

        short8 Bf[9];
        #pragma unroll
        for (int q = 0; q < 9; ++q) Bf[q] = wv8[(kp * 9 + q) * 64 + l];

        #pragma unroll
        for (int gi = GI0; gi <= GI1; ++gi) {
            const char* a = sIn + base + gi * 192;
            short8 a0 = *(const short8*)(a);        // slot(h-1): dh=0 operand
            short8 a1 = *(const short8*)(a + 16);   // slot(h):   dh=1 operand
            short8 a2 = dpp_shift<0x101>(a1);       // h+1:       dh=2 operand
            // dh-outer, dg-inner: consecutive MFMAs target different acc[t] (dep-chain distance 3).
            // Per-acc accumulation order (a0, a1, a2 for each dg) unchanged -> bit-identical.
            #pragma unroll
            for (int dh = 0; dh < 3; ++dh) {
                short8 av = (dh == 0) ? a0 : (dh == 1) ? a1 : a2;
                #pragma unroll
                for (int dg = 0; dg < 3; ++dg) {
                    int go = gi + 1 - dg;           // compile-time after unroll
                    if (go >= GO0 && go < GO0 + NT) {
                        int t = go - GO0;
                        acc[t] = __builtin_amdgcn_mfma_f32_16x16x32_bf16(av, Bf[dg * 3 + dh], acc[t], 0, 0, 0);
                    }
                }
            }
        }
    }

    // store: D col = lane&15 = co, row = kh*4+reg = h'; keep h' in [1,9]
    #pragma unroll
    for (int t = 0; t < NT; ++t) {
        int go = GO0 + t;
        int base2 = ((e_out * 12 + f_out) * P1PLANE + go * 11) * 16 + co;
        #pragma unroll
        for (int reg = 0; reg < 4; ++reg) {
            int rr = kh * 4 + reg;
            if (rr >= 1 && rr <= 9)
                gout[base2 + rr * 16] = f2bf(fmaxf(acc[t][reg], 0.f));
        }
    }
}

// ---------------- MFMA conv: 16-plane split tile, 512 thr / 8 waves, 2 blocks/CU ----------------
// block = (b, eb in {0,2,4,6,8} x fb in {0,2,4,6,8}); wave (we,wf,gs): column (eb+1+we, fb+1+wf)
__global__ __launch_bounds__(512, 4) void conv_mfma_kernel(
    const ushort_t* __restrict__ in, const uint4* __restrict__ wp,
    const float* __restrict__ bias, ushort_t* __restrict__ out) {

    __shared__ __align__(16) char sIn[LDSTILE];   // 67616 B -> 2 blocks/CU

    int tid = threadIdx.x;
    int b  = blockIdx.y;
    int eb = (blockIdx.x / 5) * 2;
    int fb = (blockIdx.x % 5) * 2;

    // ---- stage: 2112 chunks = 512*4 + 64 ----
    const ushort_t* gin = in + (size_t)b * P1POS * 16;
    #pragma unroll
    for (int k = 0; k < 4; ++k)
        stage_chunk(gin, sIn, tid + k * 512, eb, fb);
    if (tid < 64)
        stage_chunk(gin, sIn, tid + 2048, eb, fb);
    __syncthreads();   // the ONLY barrier

    int l = tid & 63, wv = tid >> 6;   // 0..7
    int col = wv >> 1, gs = wv & 1;    // column 0..3, g-half
    int we = col >> 1, wf = col & 1;
    int e_out = eb + 1 + we;
    int f_out = fb + 1 + wf;           // always in [1,10] -> no ragged waves
    float bv = bias[l & 15];

    ushort_t* gout = out + (size_t)b * P1POS * 16;
    const short8* wv8 = (const short8*)wp;

    if (gs == 0)
        conv_col<1, 5, 0, 6>(sIn, wv8, l, we, wf, bv, e_out, f_out, gout);   // go 1..5
    else
        conv_col<6, 4, 5, 10>(sIn, wv8, l, we, wf, bv, e_out, f_out, gout);  // go 6..9
}

// ---------------- fused feat(mean over ef) + fc: one block per b, 8 lanes per gh ----------------
__global__ __launch_bounds__(704) void featfc_kernel(
    const ushort_t* __restrict__ a, const float* __restrict__ fcw,
    const float* __restrict__ fcb, float* __restrict__ out) {
    int t = threadIdx.x;
    if (t >= 648) return;
    int b = blockIdx.x;
    int j = t & 7;          // ci pair index (channels 2j, 2j+1)
    int gh = t >> 3;        // 0..80
    int g = gh / 9, h = gh % 9;
    const uint_t* base = (const uint_t*)(a + (size_t)b * P1POS * 16 +
                                         (size_t)((g + 1) * 11 + (h + 1)) * 16) + j;
    float s0 = 0.f, s1 = 0.f;
    #pragma unroll 2
    for (int e = 1; e <= 10; ++e) {
        #pragma unroll
        for (int f = 1; f <= 10; ++f) {
            uint_t u = base[(size_t)(e * 12 + f) * P1PLANE * 8];
            s0 += __uint_as_float(u << 16);
            s1 += __uint_as_float(u & 0xffff0000u);
        }
    }
    s0 *= 0.01f; s1 *= 0.01f;

    float po[OUTC];
    #pragma unroll
    for (int o = 0; o < OUTC; ++o)
        po[o] = fmaf(fcw[o * 16 + 2 * j], s0, fcw[o * 16 + 2 * j + 1] * s1);
    #pragma unroll
    for (int o = 0; o < OUTC; ++o) {
        po[o] += __shfl_xor(po[o], 1);
        po[o] += __shfl_xor(po[o], 2);
        po[o] += __shfl_xor(po[o], 4);
    }
    out[((size_t)b * OUTC + j) * 81 + gh] = po[j] + fcb[j];
    if (j < 2)
        out[((size_t)b * OUTC + j + 8) * 81 + gh] = po[j + 8] + fcb[j + 8];
}

extern "C" void kernel_launch(void* const* d_in, const int* in_sizes, int n_in,
                              void* d_out, int out_size, void* d_ws, size_t ws_size,
                              hipStream_t stream) {
    const float* x   = (const float*)d_in[0];
    const float* w1  = (const float*)d_in[1];
    const float* b1  = (const float*)d_in[2];
    const float* w2  = (const float*)d_in[3];
    const float* b2  = (const float*)d_in[4];
    const float* w3  = (const float*)d_in[5];
    const float* b3  = (const float*)d_in[6];
    const float* w4  = (const float*)d_in[7];
    const float* b4  = (const float*)d_in[8];
    const float* w5  = (const float*)d_in[9];
    const float* b5  = (const float*)d_in[10];
    const float* fcw = (const float*)d_in[11];
    const float* fcb = (const float*)d_in[12];
    float* outp = (float*)d_out;

    // ---- ws layout ----
    char* wsc = (char*)d_ws;
    uint4* wp_all = (uint4*)wsc;
    size_t off = 4ull * WPL4 * sizeof(uint4);                  // 184 KB

    const size_t perb_bytes = (size_t)PFPOS * 4 + 2ull * P1POS * 16 * 2;
    size_t avail = (ws_size > off) ? ws_size - off : 0;
    int nbmax = (int)(avail / perb_bytes);
    if (nbmax < 1) nbmax = 1;
    if (nbmax > BB) nbmax = BB;

    float* bufP = (float*)(wsc + off);       off += (size_t)nbmax * PFPOS * 4;
    ushort_t* bufA = (ushort_t*)(wsc + off); off += (size_t)nbmax * P1POS * 16 * 2;
    ushort_t* bufB = (ushort_t*)(wsc + off);

    // ---- pack weights for L2..L5 (single launch) ----
    dim3 pg((WPL4 + 255) / 256, 4);
    pack_w_kernel<<<pg, 256, 0, stream>>>(w2, w3, w4, w5, wp_all);

    for (int b0 = 0; b0 < BB; b0 += nbmax) {
        int nb = BB - b0;
        if (nb > nbmax) nb = nbmax;

        int pt = nb * PFPOS;
        prep_kernel<<<(pt + 255) / 256, 256, 0, stream>>>(x + (size_t)b0 * NBANDS * 81, bufP, nb);

        dim3 c1g(4, 4, nb);
        conv1_kernel<<<c1g, 256, 0, stream>>>(bufP, w1, b1, bufA);

        dim3 mg(25, nb);
        conv_mfma_kernel<<<mg, 512, 0, stream>>>(bufA, wp_all + 0 * WPL4, b2, bufB);
        conv_mfma_kernel<<<mg, 512, 0, stream>>>(bufB, wp_all + 1 * WPL4, b3, bufA);
        conv_mfma_kernel<<<mg, 512, 0, stream>>>(bufA, wp_all + 2 * WPL4, b4, bufB);
        conv_mfma_kernel<<<mg, 512, 0, stream>>>(bufB, wp_all + 3 * WPL4, b5, bufA);

        featfc_kernel<<<nb, 704, 0, stream>>>(bufA, fcw, fcb, outp + (size_t)b0 * OUTC * 81);
    }
}